// Round 7
// baseline (122.655 us; speedup 1.0000x reference)
//
#include <hip/hip_runtime.h>
#include <hip/hip_bf16.h>
#include <stdint.h>

#define M_DIM 32
#define K_DIM 8192
#define N_DIM 8192
#define NGROUPS 64
#define KSPLIT 8
#define KPART (K_DIM / KSPLIT)     // 1024 k-values per part
#define GPART (NGROUPS / KSPLIT)   // 8 groups per part
#define BN 64

typedef __attribute__((ext_vector_type(8))) short short8;   // 8 bf16 (4 VGPRs)
typedef __attribute__((ext_vector_type(4))) float floatx4;  // MFMA acc

#define AS1(p) ((const __attribute__((address_space(1))) void*)(p))
#define AS3(p) ((__attribute__((address_space(3))) void*)(p))

// ---------------------------------------------------------------------------
// Pre-kernel: A (fp32, 32x8192) -> Abf (bf16, octet-permuted [0,4,1,5,2,6,3,7])
// and R[m][g] = sum over group g of bf16-ROUNDED A (so the +128 offset in the
// fused dequant cancels EXACTLY against 136*R).  Also zeroes d_out.
// ---------------------------------------------------------------------------
__global__ void marlin_prep_kernel(const float* __restrict__ A,
                                   uint16_t* __restrict__ Abf,
                                   float* __restrict__ R,
                                   float4* __restrict__ out4) {
    const int m = blockIdx.x;
    const int qtr = blockIdx.y;
    const int t = threadIdx.x;
    const int octet = qtr * 256 + t;     // 0..1023
    const int k0 = octet * 8;

    {   // zero out: 32768 threads * 8 floats = 262144 = M*N
        const int gtid = (qtr * 32 + m) * 256 + t;
        const float4 z = make_float4(0.f, 0.f, 0.f, 0.f);
        out4[gtid * 2] = z;
        out4[gtid * 2 + 1] = z;
    }

    const float* a = A + m * K_DIM + k0;
    uint16_t b[8];
    float sum = 0.f;
#pragma unroll
    for (int j = 0; j < 8; j++) {
        union { __hip_bfloat16 h; uint16_t u; } cv;
        cv.h = __float2bfloat16(a[j]);   // round-to-nearest bf16
        b[j] = cv.u;
        sum += __bfloat162float(cv.h);   // sum of the ROUNDED values
    }
    // pack in permuted k-order [0,4,1,5,2,6,3,7] to match nibble-pair extract
    uint32_t w0 = (uint32_t)b[0] | ((uint32_t)b[4] << 16);
    uint32_t w1 = (uint32_t)b[1] | ((uint32_t)b[5] << 16);
    uint32_t w2 = (uint32_t)b[2] | ((uint32_t)b[6] << 16);
    uint32_t w3 = (uint32_t)b[3] | ((uint32_t)b[7] << 16);
    *(uint4*)(Abf + (size_t)m * K_DIM + k0) = make_uint4(w0, w1, w2, w3);

#pragma unroll
    for (int off = 1; off < 16; off <<= 1) sum += __shfl_xor(sum, off, 16);
    if ((t & 15) == 0) R[m * NGROUPS + qtr * 16 + (t >> 4)] = sum;
}

// ---------------------------------------------------------------------------
// Main kernel: grid (N/64, KSPLIT=8) x 512 threads = 1024 blocks = 4/CU.
// R6 post-mortem: the global_load_lds restructure was coupled with KSPLIT
// 8->4 which halved occupancy (32->16 waves/CU) and regressed net (-60%).
// R7 recombines: KSPLIT=8 (1024 blocks, max TLP) + direct-to-LDS dbuf with
// the correct order per group -- barrier -> issue g+1 -> compute g -- so
// every vmcnt drain waits only on loads issued a full compute phase ago.
// LDS images XOR-swizzled on the GLOBAL side (LDS dst is forced
// wave-uniform+lane*16): A ds_read_b128 and q ds_read_b32 both exact 2-way
// bank aliasing = free.  __launch_bounds__(512,8) caps VGPR at 64 so all
// 4 blocks/CU are resident.
// ---------------------------------------------------------------------------
__global__ __launch_bounds__(512, 8) void
MarlinQuantLinear_68556267979256_kernel(const int* __restrict__ qw,
                                        const float* __restrict__ scales,
                                        const float* __restrict__ bias,
                                        const uint16_t* __restrict__ Abf,
                                        const float* __restrict__ R,
                                        float* __restrict__ out) {
    __shared__ uint32_t qbuf[2][16 * 64];   // 4 KB per buf: 16 rows x 256 B
    __shared__ uint32_t abuf[2][32 * 64];   // 8 KB per buf: 32 rows x 256 B
    __shared__ float    r_lds[32 * 9];      // 136*R, padded stride 9

    const int bx = blockIdx.x;           // n-tile block (fastest)
    const int bz = blockIdx.y;           // k-split part
    const int nbase = bx * BN;
    const int kbase = bz * KPART;        // uint16 offset into an Abf row
    const int gbase = bz * GPART;
    const int qrow0 = bz * (KPART / 8);  // first packed qweight row (128/part)

    const int tid = threadIdx.x;
    const int w = tid >> 6;
    const int lane = tid & 63;
    const int quad = lane >> 4;
    const int l16 = lane & 15;
    const int mtile = w & 1;
    const int ntile = w >> 1;
    const int ncol = nbase + ntile * 16 + l16;
    const int arow = mtile * 16 + l16;   // this lane's A row for fragments

    // stage this part's R (prescaled by 136): 32m x 8g = 256 entries
    if (tid < 256) {
        const int mm = tid >> 3, gg = tid & 7;
        r_lds[mm * 9 + gg] = 136.0f * R[mm * NGROUPS + gbase + gg];
    }

    // scale prefetch: 8 regs, in flight behind the first stage
    const float* scol = scales + (size_t)gbase * N_DIM + ncol;
    float s[GPART];
#pragma unroll
    for (int g = 0; g < GPART; g++) s[g] = scol[g * N_DIM];

    // ---- staging maps (thread -> 16B chunk), swizzle on the GLOBAL side ----
    // A: row = tid>>4 (0..31), position p = tid&15; LDS[row][p] gets global
    // chunk p ^ (row&15)  => fragment (t,quad) of row r sits at (t*4+quad)^(r&15)
    const int sra = tid >> 4, spa = tid & 15;
    const uint16_t* ga_base = Abf + (size_t)sra * K_DIM + kbase
                            + ((spa ^ (sra & 15)) << 3);       // chunk*8 bf16
    // q: rows 0..15 (tid<256), position p; LDS[row][p] gets global chunk
    // p ^ ((row&1)<<2)  => dword (R,col) sits at col ^ ((R&1)<<4)
    const int srq = tid >> 4, spq = tid & 15;
    const int* gq_base = qw + (size_t)(qrow0 + srq) * N_DIM + nbase
                       + ((spq * 4) ^ ((srq & 1) << 4));

    auto stage = [&](int g, int buf) {
        // A tile: 512 threads x 16B = 8 KB (8 wave-instructions)
        __builtin_amdgcn_global_load_lds(AS1(ga_base + g * 128),
                                         AS3(&abuf[buf][w * 256]), 16, 0, 0);
        // q tile: 256 threads x 16B = 4 KB (4 wave-instructions)
        if (tid < 256)
            __builtin_amdgcn_global_load_lds(AS1(gq_base + (size_t)g * 16 * N_DIM),
                                             AS3(&qbuf[buf][w * 256]), 16, 0, 0);
    };

    stage(0, 0);

    floatx4 C = {0.f, 0.f, 0.f, 0.f};

#pragma unroll
    for (int g = 0; g < GPART; g++) {
        __syncthreads();                 // drains loads issued one phase ago
        if (g + 1 < GPART) stage(g + 1, (g + 1) & 1);

        const uint32_t* qb = qbuf[g & 1];
        const uint32_t* ab = abuf[g & 1];
        floatx4 accg = {0.f, 0.f, 0.f, 0.f};
#pragma unroll
        for (int t = 0; t < 4; t++) {
            const uint32_t q =
                qb[(t * 4 + quad) * 64 + ((ntile * 16 + l16) ^ ((quad & 1) << 4))];
            union { uint32_t u[4]; short8 v; } fb;
            fb.u[0] = ( q        & 0x000F000Fu) | 0x43004300u;  // k0,k4
            fb.u[1] = ((q >> 4)  & 0x000F000Fu) | 0x43004300u;  // k1,k5
            fb.u[2] = ((q >> 8)  & 0x000F000Fu) | 0x43004300u;  // k2,k6
            fb.u[3] = ((q >> 12) & 0x000F000Fu) | 0x43004300u;  // k3,k7
            const short8 fa = *(const short8*)
                &ab[arow * 64 + (((t * 4 + quad) ^ (arow & 15)) << 2)];
            accg = __builtin_amdgcn_mfma_f32_16x16x32_bf16(fa, fb.v, accg, 0, 0, 0);
        }
#pragma unroll
        for (int r = 0; r < 4; r++) {
            // acc row is global m = mtile*16 + quad*4 + r; r_lds holds 136*R
            const float tval = accg[r] - r_lds[(mtile * 16 + quad * 4 + r) * 9 + g];
            C[r] = fmaf(s[g], tval, C[r]);
        }
    }

    const float bv = (bz == 0) ? bias[ncol] : 0.0f;
#pragma unroll
    for (int r = 0; r < 4; r++) {
        const int m = mtile * 16 + quad * 4 + r;   // C/D row = quad*4 + reg
        atomicAdd(&out[(size_t)m * N_DIM + ncol], C[r] + bv);
    }
}

extern "C" void kernel_launch(void* const* d_in, const int* in_sizes, int n_in,
                              void* d_out, int out_size, void* d_ws, size_t ws_size,
                              hipStream_t stream) {
    const float* A      = (const float*)d_in[0];
    const int*   qw     = (const int*)d_in[1];
    const float* scales = (const float*)d_in[2];
    const float* bias   = (const float*)d_in[3];
    float* out = (float*)d_out;

    uint16_t* Abf = (uint16_t*)d_ws;                                   // 512 KB
    float*    R   = (float*)((char*)d_ws + (size_t)M_DIM * K_DIM * 2); //   8 KB

    marlin_prep_kernel<<<dim3(M_DIM, 4), 256, 0, stream>>>(A, Abf, R, (float4*)out);
    MarlinQuantLinear_68556267979256_kernel<<<dim3(N_DIM / BN, KSPLIT), 512, 0, stream>>>(
        qw, scales, bias, Abf, R, out);
}

// Round 8
// 92.382 us; speedup vs baseline: 1.3277x; 1.3277x over previous
//
#include <hip/hip_runtime.h>
#include <hip/hip_bf16.h>
#include <stdint.h>

#define M_DIM 32
#define K_DIM 8192
#define N_DIM 8192
#define NGROUPS 64
#define KSPLIT 8
#define KPART (K_DIM / KSPLIT)     // 1024 k-values per part
#define GPART (NGROUPS / KSPLIT)   // 8 groups per part
#define BN 64

typedef __attribute__((ext_vector_type(8))) short short8;   // 8 bf16 (4 VGPRs)
typedef __attribute__((ext_vector_type(4))) float floatx4;  // MFMA acc

#define AS1(p) ((const __attribute__((address_space(1))) void*)(p))
#define AS3(p) ((__attribute__((address_space(3))) void*)(p))

// ---------------------------------------------------------------------------
// Pre-kernel: A (fp32, 32x8192) -> Abf (bf16, octet-permuted [0,4,1,5,2,6,3,7])
// and R[m][g] = sum over group g of bf16-ROUNDED A (so the +128 offset in the
// fused dequant cancels EXACTLY against 136*R).  Also zeroes d_out.
// ---------------------------------------------------------------------------
__global__ void marlin_prep_kernel(const float* __restrict__ A,
                                   uint16_t* __restrict__ Abf,
                                   float* __restrict__ R,
                                   float4* __restrict__ out4) {
    const int m = blockIdx.x;
    const int qtr = blockIdx.y;
    const int t = threadIdx.x;
    const int octet = qtr * 256 + t;     // 0..1023
    const int k0 = octet * 8;

    {   // zero out: 32768 threads * 8 floats = 262144 = M*N
        const int gtid = (qtr * 32 + m) * 256 + t;
        const float4 z = make_float4(0.f, 0.f, 0.f, 0.f);
        out4[gtid * 2] = z;
        out4[gtid * 2 + 1] = z;
    }

    const float* a = A + m * K_DIM + k0;
    uint16_t b[8];
    float sum = 0.f;
#pragma unroll
    for (int j = 0; j < 8; j++) {
        union { __hip_bfloat16 h; uint16_t u; } cv;
        cv.h = __float2bfloat16(a[j]);   // round-to-nearest bf16
        b[j] = cv.u;
        sum += __bfloat162float(cv.h);   // sum of the ROUNDED values
    }
    // pack in permuted k-order [0,4,1,5,2,6,3,7] to match nibble-pair extract
    uint32_t w0 = (uint32_t)b[0] | ((uint32_t)b[4] << 16);
    uint32_t w1 = (uint32_t)b[1] | ((uint32_t)b[5] << 16);
    uint32_t w2 = (uint32_t)b[2] | ((uint32_t)b[6] << 16);
    uint32_t w3 = (uint32_t)b[3] | ((uint32_t)b[7] << 16);
    *(uint4*)(Abf + (size_t)m * K_DIM + k0) = make_uint4(w0, w1, w2, w3);

#pragma unroll
    for (int off = 1; off < 16; off <<= 1) sum += __shfl_xor(sum, off, 16);
    if ((t & 15) == 0) R[m * NGROUPS + qtr * 16 + (t >> 4)] = sum;
}

// ---------------------------------------------------------------------------
// Main kernel: grid (N/64, KSPLIT=8) x 512 threads = 1024 blocks = 4/CU.
// R7 post-mortem: __launch_bounds__(512,8) capped VGPR at 64 -> spills
// (VGPR_Count=32, WRITE_SIZE 84 MB of scratch stores, FETCH +20 MB reloads)
// -> K-loop gained scratch round-trips, stayed latency-bound at 49 us.
// R8: SINGLE change — launch_bounds back to (512,4) (VGPR cap 128, no
// spill).  Structure unchanged: direct-to-LDS global_load_lds width=16
// double-buffer, order per group = barrier -> issue g+1 -> compute g, LDS
// images XOR-swizzled on the GLOBAL side so A ds_read_b128 / q ds_read_b32
// are exact 2-way bank aliasing (free).  LDS 26 KB -> grid-limited
// 4 blocks/CU unchanged.
// ---------------------------------------------------------------------------
__global__ __launch_bounds__(512, 4) void
MarlinQuantLinear_68556267979256_kernel(const int* __restrict__ qw,
                                        const float* __restrict__ scales,
                                        const float* __restrict__ bias,
                                        const uint16_t* __restrict__ Abf,
                                        const float* __restrict__ R,
                                        float* __restrict__ out) {
    __shared__ uint32_t qbuf[2][16 * 64];   // 4 KB per buf: 16 rows x 256 B
    __shared__ uint32_t abuf[2][32 * 64];   // 8 KB per buf: 32 rows x 256 B
    __shared__ float    r_lds[32 * 9];      // 136*R, padded stride 9

    const int bx = blockIdx.x;           // n-tile block (fastest)
    const int bz = blockIdx.y;           // k-split part
    const int nbase = bx * BN;
    const int kbase = bz * KPART;        // uint16 offset into an Abf row
    const int gbase = bz * GPART;
    const int qrow0 = bz * (KPART / 8);  // first packed qweight row (128/part)

    const int tid = threadIdx.x;
    const int w = tid >> 6;
    const int lane = tid & 63;
    const int quad = lane >> 4;
    const int l16 = lane & 15;
    const int mtile = w & 1;
    const int ntile = w >> 1;
    const int ncol = nbase + ntile * 16 + l16;
    const int arow = mtile * 16 + l16;   // this lane's A row for fragments

    // stage this part's R (prescaled by 136): 32m x 8g = 256 entries
    if (tid < 256) {
        const int mm = tid >> 3, gg = tid & 7;
        r_lds[mm * 9 + gg] = 136.0f * R[mm * NGROUPS + gbase + gg];
    }

    // scale prefetch: 8 regs, in flight behind the first stage
    const float* scol = scales + (size_t)gbase * N_DIM + ncol;
    float s[GPART];
#pragma unroll
    for (int g = 0; g < GPART; g++) s[g] = scol[g * N_DIM];

    // ---- staging maps (thread -> 16B chunk), swizzle on the GLOBAL side ----
    // A: row = tid>>4 (0..31), position p = tid&15; LDS[row][p] gets global
    // chunk p ^ (row&15)  => fragment (t,quad) of row r sits at (t*4+quad)^(r&15)
    const int sra = tid >> 4, spa = tid & 15;
    const uint16_t* ga_base = Abf + (size_t)sra * K_DIM + kbase
                            + ((spa ^ (sra & 15)) << 3);       // chunk*8 bf16
    // q: rows 0..15 (tid<256), position p; LDS[row][p] gets global chunk
    // p ^ ((row&1)<<2)  => dword (R,col) sits at col ^ ((R&1)<<4)
    const int srq = tid >> 4, spq = tid & 15;
    const int* gq_base = qw + (size_t)(qrow0 + srq) * N_DIM + nbase
                       + ((spq * 4) ^ ((srq & 1) << 4));

    auto stage = [&](int g, int buf) {
        // A tile: 512 threads x 16B = 8 KB (8 wave-instructions)
        __builtin_amdgcn_global_load_lds(AS1(ga_base + g * 128),
                                         AS3(&abuf[buf][w * 256]), 16, 0, 0);
        // q tile: 256 threads x 16B = 4 KB (4 wave-instructions)
        if (tid < 256)
            __builtin_amdgcn_global_load_lds(AS1(gq_base + (size_t)g * 16 * N_DIM),
                                             AS3(&qbuf[buf][w * 256]), 16, 0, 0);
    };

    stage(0, 0);

    floatx4 C = {0.f, 0.f, 0.f, 0.f};

#pragma unroll
    for (int g = 0; g < GPART; g++) {
        __syncthreads();                 // drains loads issued one phase ago
        if (g + 1 < GPART) stage(g + 1, (g + 1) & 1);

        const uint32_t* qb = qbuf[g & 1];
        const uint32_t* ab = abuf[g & 1];
        floatx4 accg = {0.f, 0.f, 0.f, 0.f};
#pragma unroll
        for (int t = 0; t < 4; t++) {
            const uint32_t q =
                qb[(t * 4 + quad) * 64 + ((ntile * 16 + l16) ^ ((quad & 1) << 4))];
            union { uint32_t u[4]; short8 v; } fb;
            fb.u[0] = ( q        & 0x000F000Fu) | 0x43004300u;  // k0,k4
            fb.u[1] = ((q >> 4)  & 0x000F000Fu) | 0x43004300u;  // k1,k5
            fb.u[2] = ((q >> 8)  & 0x000F000Fu) | 0x43004300u;  // k2,k6
            fb.u[3] = ((q >> 12) & 0x000F000Fu) | 0x43004300u;  // k3,k7
            const short8 fa = *(const short8*)
                &ab[arow * 64 + (((t * 4 + quad) ^ (arow & 15)) << 2)];
            accg = __builtin_amdgcn_mfma_f32_16x16x32_bf16(fa, fb.v, accg, 0, 0, 0);
        }
#pragma unroll
        for (int r = 0; r < 4; r++) {
            // acc row is global m = mtile*16 + quad*4 + r; r_lds holds 136*R
            const float tval = accg[r] - r_lds[(mtile * 16 + quad * 4 + r) * 9 + g];
            C[r] = fmaf(s[g], tval, C[r]);
        }
    }

    const float bv = (bz == 0) ? bias[ncol] : 0.0f;
#pragma unroll
    for (int r = 0; r < 4; r++) {
        const int m = mtile * 16 + quad * 4 + r;   // C/D row = quad*4 + reg
        atomicAdd(&out[(size_t)m * N_DIM + ncol], C[r] + bv);
    }
}

extern "C" void kernel_launch(void* const* d_in, const int* in_sizes, int n_in,
                              void* d_out, int out_size, void* d_ws, size_t ws_size,
                              hipStream_t stream) {
    const float* A      = (const float*)d_in[0];
    const int*   qw     = (const int*)d_in[1];
    const float* scales = (const float*)d_in[2];
    const float* bias   = (const float*)d_in[3];
    float* out = (float*)d_out;

    uint16_t* Abf = (uint16_t*)d_ws;                                   // 512 KB
    float*    R   = (float*)((char*)d_ws + (size_t)M_DIM * K_DIM * 2); //   8 KB

    marlin_prep_kernel<<<dim3(M_DIM, 4), 256, 0, stream>>>(A, Abf, R, (float4*)out);
    MarlinQuantLinear_68556267979256_kernel<<<dim3(N_DIM / BN, KSPLIT), 512, 0, stream>>>(
        qw, scales, bias, Abf, R, out);
}